// Round 8
// baseline (706.939 us; speedup 1.0000x reference)
//
#include <hip/hip_runtime.h>
#include <hip/hip_bf16.h>
#include <stdint.h>

// Problem constants (fixed by reference)
#define TOKENS_C 8192
#define NIN_C    4096
#define NOUT_C   4096
#define GROUP_C  128
#define QZERO_C  8

typedef float   f32x4  __attribute__((ext_vector_type(4)));
typedef int     i32x4  __attribute__((ext_vector_type(4)));

#define GAS __attribute__((address_space(1)))
#define LAS __attribute__((address_space(3)))

__device__ __forceinline__ void gload16(const void* g, void* l) {
  __builtin_amdgcn_global_load_lds((const GAS void*)g, (LAS void*)l, 16, 0, 0);
}

// ---------------- pass 1a: per-token quantize x -> i8 + sx -------------------
__global__ __launch_bounds__(256) void quant_x_kernel(
    const float* __restrict__ x, char* __restrict__ x8, float* __restrict__ sx)
{
  const int t   = blockIdx.x;
  const int tid = threadIdx.x;
  const float* xr = x + (size_t)t * NIN_C;
  f32x4 v[4];
#pragma unroll
  for (int r = 0; r < 4; ++r) v[r] = *(const f32x4*)(xr + tid * 16 + r * 4);
  float m = 0.f;
#pragma unroll
  for (int r = 0; r < 4; ++r)
#pragma unroll
    for (int e = 0; e < 4; ++e) m = fmaxf(m, fabsf(v[r][e]));
#pragma unroll
  for (int off = 32; off >= 1; off >>= 1) m = fmaxf(m, __shfl_xor(m, off));
  __shared__ float wmax[4];
  if ((tid & 63) == 0) wmax[tid >> 6] = m;
  __syncthreads();
  m = fmaxf(fmaxf(wmax[0], wmax[1]), fmaxf(wmax[2], wmax[3]));
  m = fmaxf(m, 1e-20f);
  const float inv = 127.0f / m;
  if (tid == 0) sx[t] = m / 127.0f;
  i32x4 o;
#pragma unroll
  for (int r = 0; r < 4; ++r) {
    int q0 = (int)rintf(v[r][0] * inv), q1 = (int)rintf(v[r][1] * inv);
    int q2 = (int)rintf(v[r][2] * inv), q3 = (int)rintf(v[r][3] * inv);
    o[r] = (q0 & 255) | ((q1 & 255) << 8) | ((q2 & 255) << 16) | ((q3 & 255) << 24);
  }
  *(i32x4*)(x8 + (size_t)t * NIN_C + tid * 16) = o;
}

// ---------------- pass 1b: repack qweight (int32 codes) -> i8 (q-8) ----------
__global__ __launch_bounds__(256) void repack_w_kernel(
    const int* __restrict__ qw, char* __restrict__ w8)
{
  const size_t base = ((size_t)blockIdx.x * 256 + threadIdx.x) * 16;
  i32x4 o;
#pragma unroll
  for (int r = 0; r < 4; ++r) {
    i32x4 q = *(const i32x4*)(qw + base + r * 4);
    o[r] = ((q[0] - QZERO_C) & 255) | (((q[1] - QZERO_C) & 255) << 8) |
           (((q[2] - QZERO_C) & 255) << 16) | (((q[3] - QZERO_C) & 255) << 24);
  }
  *(i32x4*)(w8 + base) = o;
}

// ---------------- pass 1c: transpose scales [NOUT][32] -> sT[32][NOUT] -------
__global__ __launch_bounds__(256) void tsc_kernel(
    const float* __restrict__ sc, float* __restrict__ sT)
{
  const int id = blockIdx.x * 256 + threadIdx.x;   // over 32*4096
  const int o = id & (NOUT_C - 1), g = id >> 12;
  sT[id] = sc[o * (NIN_C / GROUP_C) + g];
}

// ---------------- pass 2: i8 GEMM, C[t,o] = sx[t] * sum_g sT[g][o]*dot_g -----
// 256x256 tile, BK=128 (= one GPTQ group), 512 threads (8 waves 2Mx4N),
// dbuf LDS 128KB (i8: tile-operand 256x128B = 32KB), R7's 2-barrier/tile
// skeleton, 0-conflict XOR swizzle (128B rows, granule ^= row&7), counted
// vmcnt(4) never 0 in main loop. Per tile: i32 group-dot via
// mfma_i32_16x16x64_i8 (2 per output frag), then facc += cvt(i32)*s[o,g].
#define BM 256
#define BN 256
#define BKB 128                    // K bytes per tile (i8)
#define NT (NIN_C / BKB)           // 32 tiles

__global__ __launch_bounds__(512, 2) void gemm_i8_kernel(
    const char* __restrict__ A,    // x8 [M][K] i8
    const char* __restrict__ B,    // w8 [N][K] i8
    const float* __restrict__ sTg, // [32][NOUT]
    const float* __restrict__ sx,  // [M]
    float* __restrict__ C)         // [M][N] f32
{
  constexpr int N = NOUT_C, KB = NIN_C;  // K bytes per row
  // A: parity p at smem + p*32768 ; B: parity p at smem + 65536 + p*32768
  __shared__ char smem[131072];

  const int tid  = threadIdx.x;
  const int lane = tid & 63;
  const int wid  = tid >> 6;
  const int wm   = wid >> 2;       // 0..1 -> 128 rows of C
  const int wn   = wid & 3;        // 0..3 -> 64 cols of C
  const int bm   = blockIdx.x;
  const int bn   = blockIdx.y;

  const int frow  = lane & 15;
  const int klane = lane >> 4;     // 0..3
  const int swr   = lane & 7;      // row&7 for fragment rows (row%8==lane%8)

  // staging: tile-operand 256 rows x 128B; halves h (128 rows, 16KB, 2 gloads)
  // thread -> slot wid*2+l (8 rows x 128B); row = h*128+slot*8+(lane>>3),
  // granule lane&7 pre-swizzled with involution g ^= (row&7)==(lane>>3).
  const int cswz = (((lane & 7) ^ (lane >> 3)) << 4);
  int64_t aso[2][2], bso[2][2];
#pragma unroll
  for (int h = 0; h < 2; ++h)
#pragma unroll
    for (int l = 0; l < 2; ++l) {
      const int r = h * 128 + (wid * 2 + l) * 8 + (lane >> 3);
      aso[h][l] = (int64_t)(bm * BM + r) * KB + cswz;
      bso[h][l] = (int64_t)(bn * BN + r) * KB + cswz;
    }
  const int sdst = wid * 2048 + (lane << 4);

#define STG_A(tt, h) { char* d_ = smem + (((tt) & 1) << 15) + ((h) << 14) + sdst; \
    gload16(A + aso[h][0] + (tt) * BKB, d_);                                      \
    gload16(A + aso[h][1] + (tt) * BKB, d_ + 1024); }
#define STG_B(tt, h) { char* d_ = smem + 65536 + (((tt) & 1) << 15) + ((h) << 14) + sdst; \
    gload16(B + bso[h][0] + (tt) * BKB, d_);                                      \
    gload16(B + bso[h][1] + (tt) * BKB, d_ + 1024); }

  const int ccol0 = bn * BN + wn * 64;

#define LD_S(dst, g)                                                           \
  _Pragma("unroll")                                                            \
  for (int j_ = 0; j_ < 4; ++j_)                                               \
    dst[j_] = sTg[(size_t)(g) * NOUT_C + ccol0 + j_ * 16 + frow];

  // fragment reads (i8 16x16x64: lane holds 16 contiguous k at k0=klane*16;
  // granule = (ks*4+klane) ^ (row&7), row%8 == lane%8)
#define ARD(Ad, ii, ks) (*(const i32x4*)((Ad) + ((ii) * 16 + frow) * 128 +     \
                         (((((ks) << 2) | klane) ^ swr) << 4)))
  i32x4 bf[4][2];
#define BRD_ALL(Bd)                                                            \
  _Pragma("unroll")                                                            \
  for (int j_ = 0; j_ < 4; ++j_) {                                             \
    bf[j_][0] = *(const i32x4*)((Bd) + (j_ * 16 + frow) * 128 + ((klane ^ swr) << 4)); \
    bf[j_][1] = *(const i32x4*)((Bd) + (j_ * 16 + frow) * 128 + (((4 | klane) ^ swr) << 4)); }

  f32x4 facc[8][4] = {};
  const i32x4 zq = {0, 0, 0, 0};

#define MFI(a_, b_, c_) __builtin_amdgcn_mfma_i32_16x16x64_i8(a_, b_, c_, 0, 0, 0)
#define SC_APPLY(ii, jj, tv, scur)                                             \
  { f32x4 tf_;                                                                 \
    tf_[0] = (float)(tv)[0]; tf_[1] = (float)(tv)[1];                          \
    tf_[2] = (float)(tv)[2]; tf_[3] = (float)(tv)[3];                          \
    facc[ii][jj] += tf_ * (scur)[jj]; }
#define DO_I(ii, Ad, scur)                                                     \
  { i32x4 ak0_ = ARD(Ad, ii, 0), ak1_ = ARD(Ad, ii, 1);                        \
    i32x4 t0_, t1_, t2_, t3_;                                                  \
    __builtin_amdgcn_s_setprio(1);                                             \
    t0_ = MFI(ak0_, bf[0][0], zq); t0_ = MFI(ak1_, bf[0][1], t0_);             \
    t1_ = MFI(ak0_, bf[1][0], zq); t1_ = MFI(ak1_, bf[1][1], t1_);             \
    t2_ = MFI(ak0_, bf[2][0], zq); t2_ = MFI(ak1_, bf[2][1], t2_);             \
    t3_ = MFI(ak0_, bf[3][0], zq); t3_ = MFI(ak1_, bf[3][1], t3_);             \
    __builtin_amdgcn_s_setprio(0);                                             \
    SC_APPLY(ii, 0, t0_, scur); SC_APPLY(ii, 1, t1_, scur);                    \
    SC_APPLY(ii, 2, t2_, scur); SC_APPLY(ii, 3, t3_, scur); }

#define BAR __builtin_amdgcn_s_barrier()
#define WAITV(n) asm volatile("s_waitcnt vmcnt(" #n ")" ::: "memory")
#define SBAR0 __builtin_amdgcn_sched_barrier(0)

  float sA[4], sB[4];

  // ---- prologue: s(0) loads FIRST (oldest in queue), then A(0),B(0),B(1) ---
  LD_S(sA, 0);
  SBAR0;
  STG_A(0, 0); STG_A(0, 1);
  STG_B(0, 0); STG_B(0, 1);
  STG_B(1, 0); STG_B(1, 1);
  WAITV(4);                 // 16 issued; retire s0+A0+B0, keep B(1) flying
  BAR; SBAR0;

  // One tile: ph1-3 barrier-free, mid-BAR, ph4, counted WAITV, end-BAR.
  // in-flight ledger entering tile t: [B(t+1)]=4. +s(t+1)+A(t+1)+B(t+2)=16;
  // WAITV(4) retires s+A+B(t+1-wave), keeps B(t+2). Never 0 in main loop.
#define TILE(tt, par, scur, snxt, DO_SN, DO_SA, DO_SB, WVN)                    \
  {                                                                            \
    const char* Ad_ = smem + (par) * 32768 + wm * 16384;                       \
    const char* Bd_ = smem + 65536 + (par) * 32768 + wn * 8192;                \
    if (DO_SN) { LD_S(snxt, (tt) + 1); }                                       \
    BRD_ALL(Bd_);                                                              \
    if (DO_SA) { STG_A((tt) + 1, 0); }                                         \
    DO_I(0, Ad_, scur); DO_I(1, Ad_, scur);                                    \
    if (DO_SA) { STG_A((tt) + 1, 1); }                                         \
    DO_I(2, Ad_, scur); DO_I(3, Ad_, scur);                                    \
    DO_I(4, Ad_, scur); DO_I(5, Ad_, scur);                                    \
    SBAR0; BAR;                                                                \
    if (DO_SB) { STG_B((tt) + 2, 0); STG_B((tt) + 2, 1); }                     \
    DO_I(6, Ad_, scur); DO_I(7, Ad_, scur);                                    \
    WAITV(WVN); SBAR0; BAR;                                                    \
  }

  for (int t0 = 0; t0 < NT - 2; t0 += 2) {
    TILE(t0,     0, sA, sB, 1, 1, 1, 4);
    TILE(t0 + 1, 1, sB, sA, 1, 1, 1, 4);
  }
  // tile NT-2 = 30 (par 0): stage A(31) + s(31); no B-stage; full drain
  TILE(NT - 2, 0, sA, sB, 1, 1, 0, 0);
  // tile NT-1 = 31 (par 1): no stages, no barriers
  {
    const char* Ad_ = smem + 32768 + wm * 16384;
    const char* Bd_ = smem + 65536 + 32768 + wn * 8192;
    BRD_ALL(Bd_);
    DO_I(0, Ad_, sB); DO_I(1, Ad_, sB); DO_I(2, Ad_, sB); DO_I(3, Ad_, sB);
    DO_I(4, Ad_, sB); DO_I(5, Ad_, sB); DO_I(6, Ad_, sB); DO_I(7, Ad_, sB);
  }

  // ---- epilogue: C = sx[row] * facc. C/D: col=lane&15, row=(lane>>4)*4+r ---
  const int crow0 = bm * BM + wm * 128;
  const int r0 = (lane >> 4) << 2;
#pragma unroll
  for (int fi = 0; fi < 8; ++fi) {
    const f32x4 sxv = *(const f32x4*)(sx + crow0 + fi * 16 + r0);
#pragma unroll
    for (int j = 0; j < 4; ++j) {
      f32x4 v = facc[fi][j];
#pragma unroll
      for (int r = 0; r < 4; ++r)
        C[(int64_t)(crow0 + fi * 16 + r0 + r) * N + (ccol0 + j * 16 + frow)] =
            v[r] * sxv[r];
    }
  }
#undef STG_A
#undef STG_B
#undef LD_S
#undef ARD
#undef BRD_ALL
#undef MFI
#undef SC_APPLY
#undef DO_I
#undef TILE
#undef BAR
#undef WAITV
#undef SBAR0
}

// ---------------- fallback (only if ws too small): naive fp32 ---------------
__global__ __launch_bounds__(256) void naive_kernel(
    const float* __restrict__ x, const int* __restrict__ qw,
    const float* __restrict__ sc, float* __restrict__ out)
{
  const int64_t idx = (int64_t)blockIdx.x * 256 + threadIdx.x;
  const int tok = (int)(idx >> 12);
  const int o   = (int)(idx & 4095);
  const float* xr = x + (int64_t)tok * NIN_C;
  const int* qr = qw + (int64_t)o * NIN_C;
  float acc = 0.f;
  for (int g = 0; g < NIN_C / GROUP_C; ++g) {
    float s = sc[(o << 5) | g];
    float ga = 0.f;
#pragma unroll 4
    for (int i = g * GROUP_C; i < (g + 1) * GROUP_C; ++i)
      ga += xr[i] * (float)(qr[i] - QZERO_C);
    acc += s * ga;
  }
  out[idx] = acc;
}

extern "C" void kernel_launch(void* const* d_in, const int* in_sizes, int n_in,
                              void* d_out, int out_size, void* d_ws, size_t ws_size,
                              hipStream_t stream) {
  const float* x  = (const float*)d_in[0];
  const int*   qw = (const int*)d_in[1];
  const float* sc = (const float*)d_in[2];
  float* out = (float*)d_out;

  const size_t x8_bytes = (size_t)TOKENS_C * NIN_C;          // 32 MiB
  const size_t w8_bytes = (size_t)NOUT_C * NIN_C;            // 16 MiB
  const size_t sx_bytes = (size_t)TOKENS_C * sizeof(float);  // 32 KiB
  const size_t sT_bytes = (size_t)(NIN_C / GROUP_C) * NOUT_C * sizeof(float);

  if (ws_size < x8_bytes + w8_bytes + sx_bytes + sT_bytes) {
    const int64_t total = (int64_t)TOKENS_C * NOUT_C;
    naive_kernel<<<(int)(total / 256), 256, 0, stream>>>(x, qw, sc, out);
    return;
  }

  char*  x8 = (char*)d_ws;
  char*  w8 = (char*)d_ws + x8_bytes;
  float* sx = (float*)((char*)d_ws + x8_bytes + w8_bytes);
  float* sT = (float*)((char*)d_ws + x8_bytes + w8_bytes + sx_bytes);

  quant_x_kernel<<<TOKENS_C, 256, 0, stream>>>(x, x8, sx);
  repack_w_kernel<<<(int)(w8_bytes / 16 / 256), 256, 0, stream>>>(qw, w8);
  tsc_kernel<<<(int)((NIN_C / GROUP_C) * NOUT_C / 256), 256, 0, stream>>>(sc, sT);
  {
    dim3 grid(TOKENS_C / BM, NOUT_C / BN);   // 32 x 16 = 512 wg
    gemm_i8_kernel<<<grid, 512, 0, stream>>>(x8, w8, sT, sx, out);
  }
}